// Round 17
// baseline (412.990 us; speedup 1.0000x reference)
//
#include <hip/hip_runtime.h>
#include <hip/hip_fp16.h>
#include <math.h>

#define HDIM 128
#define BKT_SHIFT 7          // 128 nodes per bucket
#define NBMAX 512            // max buckets (N <= 65536)
#define CHUNK 4096           // edges per bucket_scatter block
#define NBS 512              // bn_stats blocks (= partial rows)

typedef __attribute__((ext_vector_type(8))) short bf16x8;
typedef __attribute__((ext_vector_type(4))) float f32x4;

union U4 { unsigned int u[4]; bf16x8 v; };

__device__ __forceinline__ unsigned int cvt_pk_bf16(float a, float b) {
    unsigned int r;
    asm("v_cvt_pk_bf16_f32 %0, %1, %2" : "=v"(r) : "v"(a), "v"(b));
    return r;
}

// split 8 fp32 -> hi bf16x8 + lo bf16x8 (x ~= hi + lo, error ~2^-17 |x|)
__device__ __forceinline__ void split8(const float* v, bf16x8& ah, bf16x8& al) {
    U4 H, L;
    #pragma unroll
    for (int p = 0; p < 4; p++) {
        unsigned int h = cvt_pk_bf16(v[2 * p], v[2 * p + 1]);
        H.u[p] = h;
        float h0 = __uint_as_float(h << 16);
        float h1 = __uint_as_float(h & 0xFFFF0000u);
        L.u[p] = cvt_pk_bf16(v[2 * p] - h0, v[2 * p + 1] - h1);
    }
    ah = H.v; al = L.v;
}

// ================= CSR build via two-level binning =================
__global__ __launch_bounds__(256) void bucket_hist(const int* __restrict__ dst,
                                                   int* __restrict__ bcount, int E) {
    __shared__ int h[NBMAX];
    int t = threadIdx.x;
    for (int b = t; b < NBMAX; b += 256) h[b] = 0;
    __syncthreads();
    int i = blockIdx.x * blockDim.x + t;
    int stride = gridDim.x * blockDim.x;
    for (; i < E; i += stride) atomicAdd(&h[dst[i] >> BKT_SHIFT], 1);
    __syncthreads();
    for (int b = t; b < NBMAX; b += 256) {
        int c = h[b];
        if (c) atomicAdd(&bcount[b], c);
    }
}

__global__ __launch_bounds__(256) void bucket_scan(const int* __restrict__ bcount,
                                                   int* __restrict__ bases,
                                                   int* __restrict__ cursor, int E) {
    int t = threadIdx.x;
    int v0 = bcount[2 * t], v1 = bcount[2 * t + 1];
    int s = v0 + v1;
    __shared__ int ss[256];
    ss[t] = s; __syncthreads();
    #pragma unroll
    for (int off = 1; off < 256; off <<= 1) {
        int u = (t >= off) ? ss[t - off] : 0;
        __syncthreads();
        ss[t] += u;
        __syncthreads();
    }
    int ex = ss[t] - s;
    bases[2 * t] = ex;          cursor[2 * t] = ex;
    bases[2 * t + 1] = ex + v0; cursor[2 * t + 1] = ex + v0;
    if (t == 255) bases[NBMAX] = E;
}

// pack: bits 24..30 = dst&127, bits 0..23 = src  (requires N < 2^24)
__global__ __launch_bounds__(256) void bucket_scatter(const int* __restrict__ src,
                                                      const int* __restrict__ dst,
                                                      int* __restrict__ cursor,
                                                      unsigned* __restrict__ ebuf, int E) {
    __shared__ unsigned sbuf[CHUNK];
    __shared__ int hist[NBMAX], hbase[NBMAX], gbase[NBMAX], cnt2[NBMAX];
    __shared__ int ss[256];
    int t = threadIdx.x;
    int start = blockIdx.x * CHUNK;
    int n = min(CHUNK, E - start);

    for (int b = t; b < NBMAX; b += 256) { hist[b] = 0; cnt2[b] = 0; }
    __syncthreads();
    for (int i = t; i < n; i += 256) atomicAdd(&hist[dst[start + i] >> BKT_SHIFT], 1);
    __syncthreads();

    int v0 = hist[2 * t], v1 = hist[2 * t + 1];
    int s = v0 + v1;
    ss[t] = s; __syncthreads();
    #pragma unroll
    for (int off = 1; off < 256; off <<= 1) {
        int u = (t >= off) ? ss[t - off] : 0;
        __syncthreads();
        ss[t] += u;
        __syncthreads();
    }
    int ex = ss[t] - s;
    hbase[2 * t] = ex;
    hbase[2 * t + 1] = ex + v0;
    if (v0 > 0) gbase[2 * t] = atomicAdd(&cursor[2 * t], v0);
    if (v1 > 0) gbase[2 * t + 1] = atomicAdd(&cursor[2 * t + 1], v1);
    __syncthreads();

    for (int i = t; i < n; i += 256) {
        int d = dst[start + i];
        int bkt = d >> BKT_SHIFT;
        unsigned p = ((unsigned)(d & 127) << 24) | (unsigned)src[start + i];
        int pos = atomicAdd(&cnt2[bkt], 1);
        sbuf[hbase[bkt] + pos] = p;
    }
    __syncthreads();

    for (int b = t; b < NBMAX; b += 256) {
        int c = hist[b], hb = hbase[b], gb = gbase[b];
        for (int j = 0; j < c; j++) ebuf[gb + j] = sbuf[hb + j];
    }
}

__global__ __launch_bounds__(256) void bucket_finalize(const unsigned* __restrict__ ebuf,
                                                       const int* __restrict__ bases,
                                                       int* __restrict__ csr,
                                                       int* __restrict__ offs,
                                                       float* __restrict__ dinv,
                                                       int N, int E) {
    int b = blockIdx.x;
    int beg = bases[b], end = bases[b + 1];
    __shared__ int hist[128], pre[128], cnt2[128];
    int t = threadIdx.x;
    if (t < 128) { hist[t] = 0; cnt2[t] = 0; }
    __syncthreads();
    for (int i = beg + t; i < end; i += 256)
        atomicAdd(&hist[(ebuf[i] >> 24) & 127], 1);
    __syncthreads();
    if (t < 128) pre[t] = hist[t];
    __syncthreads();
    #pragma unroll
    for (int off = 1; off < 128; off <<= 1) {
        int v = (t < 128 && t >= off) ? pre[t - off] : 0;
        __syncthreads();
        if (t < 128) pre[t] += v;
        __syncthreads();
    }
    if (t < 128) {
        int node = b * 128 + t;
        if (node < N) {
            int ex = pre[t] - hist[t];
            offs[node] = beg + ex;
            dinv[node] = rsqrtf((float)hist[t] + 1.0f);
        }
    }
    if (b == 0 && t == 0) offs[N] = E;
    __syncthreads();
    for (int i = beg + t; i < end; i += 256) {
        unsigned p = ebuf[i];
        int dl = (p >> 24) & 127;
        int pos = atomicAdd(&cnt2[dl], 1);
        csr[beg + (pre[dl] - hist[dl]) + pos] = (int)(p & 0xFFFFFFu);
    }
}

// ---------------- weight split (all 5 matrices, unscaled) ----------------
__global__ void wsplit_all(const float* __restrict__ W_emb, const float* __restrict__ W_conv,
                           short* __restrict__ wt) {
    int gid = blockIdx.x * 256 + threadIdx.x;
    if (gid >= 5 * 16384) return;
    int m = gid >> 14;
    int i = gid & 16383;               // i = n*128 + k
    int n = i >> 7, k = i & 127;
    const float* src = (m == 0) ? W_emb : (W_conv + (size_t)(m - 1) * 16384);
    float v = src[k * 128 + n];
    unsigned int u = __float_as_uint(v);
    unsigned int hi = (u + 0x7FFFu + ((u >> 16) & 1)) & 0xFFFF0000u;
    float hf = __uint_as_float(hi);
    float lo = v - hf;
    unsigned int ul = __float_as_uint(lo);
    unsigned int lo16 = (ul + 0x7FFFu + ((ul >> 16) & 1)) >> 16;
    short* Whi = wt + (size_t)m * 32768;
    Whi[i] = (short)(hi >> 16);
    Whi[16384 + i] = (short)lo16;
}

// ---------------- BN-scaled weight split: W'[n][k] = W[k][n]*aff_s[k] ----------------
__global__ void wsplit_scaled(const float* __restrict__ Wsrc, const float* __restrict__ aff_s,
                              short* __restrict__ Whi) {
    int i = blockIdx.x * 256 + threadIdx.x;   // i = n*128 + k
    if (i >= 16384) return;
    int n = i >> 7, k = i & 127;
    float v = Wsrc[k * 128 + n] * aff_s[k];
    unsigned int u = __float_as_uint(v);
    unsigned int hi = (u + 0x7FFFu + ((u >> 16) & 1)) & 0xFFFF0000u;
    float hf = __uint_as_float(hi);
    float lo = v - hf;
    unsigned int ul = __float_as_uint(lo);
    unsigned int lo16 = (ul + 0x7FFFu + ((ul >> 16) & 1)) >> 16;
    Whi[i] = (short)(hi >> 16);
    Whi[16384 + i] = (short)lo16;
}

// ---------------- MFMA GEMM: C[N x 128] = A[N x 128] @ W[128 x 128] (+colbias)(*rowscale) ----
// IN_SPLIT: A given as bf16 hi/lo arrays (Ahi, Ahi+NH) — no VALU split in hot loop.
// OUT_SPLIT: write bf16 hi/lo (next GEMM's A); else write fp16 (gather input).
template <bool IN_SPLIT, bool OUT_SPLIT>
__global__ __launch_bounds__(256) void gemm_mfma(const void* __restrict__ Ap,
                                                 const short* __restrict__ Wh,
                                                 const short* __restrict__ Wl,
                                                 const float* __restrict__ bias,
                                                 const float* __restrict__ rowscale,
                                                 void* __restrict__ outp,
                                                 size_t NH, int N) {
    int w = threadIdx.x >> 6;
    int lane = threadIdx.x & 63;
    int l15 = lane & 15, lg = lane >> 4;
    int r0 = blockIdx.x * 128 + (w >> 1) * 64;
    int c0 = (w & 1) * 64;

    f32x4 acc[4][4];
    #pragma unroll
    for (int tc = 0; tc < 4; tc++) {
        float bz = bias ? bias[c0 + tc * 16 + l15] : 0.0f;
        #pragma unroll
        for (int tr = 0; tr < 4; tr++) {
            acc[tr][tc][0] = bz; acc[tr][tc][1] = bz;
            acc[tr][tc][2] = bz; acc[tr][tc][3] = bz;
        }
    }

    #pragma unroll
    for (int kt = 0; kt < 4; kt++) {
        int kk = kt * 32 + lg * 8;

        bf16x8 bh[4], bl[4];
        #pragma unroll
        for (int tc = 0; tc < 4; tc++) {
            int n = c0 + tc * 16 + l15;
            bh[tc] = *(const bf16x8*)(Wh + n * 128 + kk);
            bl[tc] = *(const bf16x8*)(Wl + n * 128 + kk);
        }

        bf16x8 ah[4], al[4];
        #pragma unroll
        for (int tr = 0; tr < 4; tr++) {
            int row = min(r0 + tr * 16 + l15, N - 1);
            if (IN_SPLIT) {
                const short* Ahi = (const short*)Ap;
                ah[tr] = *(const bf16x8*)(Ahi + (size_t)row * 128 + kk);
                al[tr] = *(const bf16x8*)(Ahi + NH + (size_t)row * 128 + kk);
            } else {
                const float* ap = (const float*)Ap + (size_t)row * 128 + kk;
                float v[8];
                *(float4*)&v[0] = *(const float4*)ap;
                *(float4*)&v[4] = *(const float4*)(ap + 4);
                split8(v, ah[tr], al[tr]);
            }
        }

        #pragma unroll
        for (int tr = 0; tr < 4; tr++) {
            #pragma unroll
            for (int tc = 0; tc < 4; tc++) {
                acc[tr][tc] = __builtin_amdgcn_mfma_f32_16x16x32_bf16(ah[tr], bh[tc], acc[tr][tc], 0, 0, 0);
                acc[tr][tc] = __builtin_amdgcn_mfma_f32_16x16x32_bf16(ah[tr], bl[tc], acc[tr][tc], 0, 0, 0);
                acc[tr][tc] = __builtin_amdgcn_mfma_f32_16x16x32_bf16(al[tr], bh[tc], acc[tr][tc], 0, 0, 0);
            }
        }
    }

    // C/D layout: row = (lane>>4)*4 + reg, col = lane&15 (per 16x16 tile)
    #pragma unroll
    for (int tr = 0; tr < 4; tr++) {
        #pragma unroll
        for (int r = 0; r < 4; r++) {
            int row = r0 + tr * 16 + lg * 4 + r;
            if (row < N) {
                float sc = rowscale ? rowscale[row] : 1.0f;
                #pragma unroll
                for (int tc = 0; tc < 4; tc++) {
                    int col = c0 + tc * 16 + l15;
                    float val = acc[tr][tc][r] * sc;
                    if (OUT_SPLIT) {
                        unsigned int u = __float_as_uint(val);
                        unsigned int hi = (u + 0x7FFFu + ((u >> 16) & 1)) & 0xFFFF0000u;
                        float lof = val - __uint_as_float(hi);
                        unsigned int ul = __float_as_uint(lof);
                        unsigned int lo16 = (ul + 0x7FFFu + ((ul >> 16) & 1)) >> 16;
                        short* Ohi = (short*)outp;
                        Ohi[(size_t)row * 128 + col] = (short)(hi >> 16);
                        Ohi[NH + (size_t)row * 128 + col] = (short)lo16;
                    } else {
                        ((__half*)outp)[(size_t)row * 128 + col] = __float2half(val);
                    }
                }
            }
        }
    }
}

// ---------------- gather (fp16 in), 2 edges/wave via 8B lane loads ----------------
// OUT_SPLIT: relu + write bf16 hi/lo (feeds next GEMM); else write fp32 (feeds pool).
template <bool OUT_SPLIT>
__global__ __launch_bounds__(256) void gather_kernel(const __half* __restrict__ hws,
                                                     const int* __restrict__ csr_src,
                                                     const int* __restrict__ offs,
                                                     const float* __restrict__ dinv,
                                                     const float* __restrict__ bias,
                                                     void* __restrict__ outp,
                                                     size_t NH, int N) {
    int lane = threadIdx.x & 63;
    int half = lane >> 5;
    int sl = lane & 31;
    int node = blockIdx.x * 4 + (threadIdx.x >> 6);
    if (node >= N) return;
    int lo = offs[node], hi = offs[node + 1];

    const uint2* base = (const uint2*)hws;  // row s = base + s*32; lane offset sl
    float4 acc = make_float4(0.f, 0.f, 0.f, 0.f);

    int j = lo + half;
    for (; j + 6 < hi; j += 8) {
        int s0 = csr_src[j], s1 = csr_src[j + 2], s2 = csr_src[j + 4], s3 = csr_src[j + 6];
        uint2 u0 = base[(size_t)s0 * 32 + sl];
        uint2 u1 = base[(size_t)s1 * 32 + sl];
        uint2 u2 = base[(size_t)s2 * 32 + sl];
        uint2 u3 = base[(size_t)s3 * 32 + sl];
        float2 a0 = __half22float2(*(__half2*)&u0.x), b0 = __half22float2(*(__half2*)&u0.y);
        float2 a1 = __half22float2(*(__half2*)&u1.x), b1 = __half22float2(*(__half2*)&u1.y);
        float2 a2 = __half22float2(*(__half2*)&u2.x), b2 = __half22float2(*(__half2*)&u2.y);
        float2 a3 = __half22float2(*(__half2*)&u3.x), b3 = __half22float2(*(__half2*)&u3.y);
        acc.x += a0.x + a1.x + a2.x + a3.x;
        acc.y += a0.y + a1.y + a2.y + a3.y;
        acc.z += b0.x + b1.x + b2.x + b3.x;
        acc.w += b0.y + b1.y + b2.y + b3.y;
    }
    for (; j < hi; j += 2) {
        int s = csr_src[j];
        uint2 u = base[(size_t)s * 32 + sl];
        float2 a = __half22float2(*(__half2*)&u.x), b = __half22float2(*(__half2*)&u.y);
        acc.x += a.x; acc.y += a.y; acc.z += b.x; acc.w += b.y;
    }
    // self-loop: half 0 only
    if (half == 0) {
        uint2 u = base[(size_t)node * 32 + sl];
        float2 a = __half22float2(*(__half2*)&u.x), b = __half22float2(*(__half2*)&u.y);
        acc.x += a.x; acc.y += a.y; acc.z += b.x; acc.w += b.y;
    }
    acc.x += __shfl_xor(acc.x, 32);
    acc.y += __shfl_xor(acc.y, 32);
    acc.z += __shfl_xor(acc.z, 32);
    acc.w += __shfl_xor(acc.w, 32);

    if (half == 0) {
        float di = dinv[node];
        float4 b = ((const float4*)bias)[sl];
        float ox = di * acc.x + b.x;
        float oy = di * acc.y + b.y;
        float oz = di * acc.z + b.z;
        float ow = di * acc.w + b.w;
        if (OUT_SPLIT) {
            ox = fmaxf(ox, 0.f); oy = fmaxf(oy, 0.f);
            oz = fmaxf(oz, 0.f); ow = fmaxf(ow, 0.f);
            unsigned h0 = cvt_pk_bf16(ox, oy), h1 = cvt_pk_bf16(oz, ow);
            float hx = __uint_as_float(h0 << 16), hy = __uint_as_float(h0 & 0xFFFF0000u);
            float hz = __uint_as_float(h1 << 16), hw = __uint_as_float(h1 & 0xFFFF0000u);
            unsigned l0 = cvt_pk_bf16(ox - hx, oy - hy), l1 = cvt_pk_bf16(oz - hz, ow - hw);
            short* Ohi = (short*)outp;
            ((uint2*)(Ohi + (size_t)node * 128))[sl] = make_uint2(h0, h1);
            ((uint2*)(Ohi + NH + (size_t)node * 128))[sl] = make_uint2(l0, l1);
        } else {
            ((float4*)((float*)outp + (size_t)node * HDIM))[sl] = make_float4(ox, oy, oz, ow);
        }
    }
}

// ---------------- BN stats from split h: 512 blocks, 4-way MLP, no atomics ----------------
__global__ __launch_bounds__(256) void bn_stats2(const short* __restrict__ Ahi,
                                                 float* __restrict__ Psum,
                                                 float* __restrict__ Qsum,
                                                 size_t NH, int N) {
    int sl = threadIdx.x & 31;   // feature quad 4sl..4sl+3
    int rg = threadIdx.x >> 5;   // row group 0..7
    const short* Alo = Ahi + NH;
    float4 s = make_float4(0.f, 0.f, 0.f, 0.f), q = s;
    const int S = NBS * 8;       // 4096
    for (int n = blockIdx.x * 8 + rg; n < N; n += 4 * S) {
        #pragma unroll
        for (int u = 0; u < 4; u++) {
            int nn = n + u * S;
            if (nn < N) {
                uint2 uh = ((const uint2*)(Ahi + (size_t)nn * 128))[sl];
                uint2 ul = ((const uint2*)(Alo + (size_t)nn * 128))[sl];
                float vx = __uint_as_float(uh.x << 16) + __uint_as_float(ul.x << 16);
                float vy = __uint_as_float(uh.x & 0xFFFF0000u) + __uint_as_float(ul.x & 0xFFFF0000u);
                float vz = __uint_as_float(uh.y << 16) + __uint_as_float(ul.y << 16);
                float vw = __uint_as_float(uh.y & 0xFFFF0000u) + __uint_as_float(ul.y & 0xFFFF0000u);
                s.x += vx; q.x += vx * vx;
                s.y += vy; q.y += vy * vy;
                s.z += vz; q.z += vz * vz;
                s.w += vw; q.w += vw * vw;
            }
        }
    }
    __shared__ float4 rs[256], rq[256];
    rs[threadIdx.x] = s; rq[threadIdx.x] = q;
    __syncthreads();
    #pragma unroll
    for (int off = 4; off >= 1; off >>= 1) {
        if (rg < off) {
            float4 os = rs[threadIdx.x + off * 32], oq = rq[threadIdx.x + off * 32];
            s.x += os.x; s.y += os.y; s.z += os.z; s.w += os.w;
            q.x += oq.x; q.y += oq.y; q.z += oq.z; q.w += oq.w;
            rs[threadIdx.x] = s; rq[threadIdx.x] = q;
        }
        __syncthreads();
    }
    if (rg == 0) {
        size_t base = (size_t)blockIdx.x * HDIM;
        ((float4*)(Psum + base))[sl] = s;
        ((float4*)(Qsum + base))[sl] = q;
    }
}

// ---------------- bn finalize: coalesced partial reduce + rank-1 fold c = t @ Wnext ----------------
__global__ __launch_bounds__(256) void bn_finalize_w(const float* __restrict__ Psum,
                                                     const float* __restrict__ Qsum,
                                                     const float* __restrict__ gamma,
                                                     const float* __restrict__ beta,
                                                     const float* __restrict__ Wnext,
                                                     float* __restrict__ aff_s,
                                                     float* __restrict__ cvec,
                                                     int N, int nblk) {
    int t = threadIdx.x;
    int total4 = nblk * 32;  // float4 elements per array
    float4 s = make_float4(0.f, 0.f, 0.f, 0.f), q = s;
    for (int i = t; i < total4; i += 256) {
        float4 p = ((const float4*)Psum)[i];
        float4 r = ((const float4*)Qsum)[i];
        s.x += p.x; s.y += p.y; s.z += p.z; s.w += p.w;
        q.x += r.x; q.y += r.y; q.z += r.z; q.w += r.w;
    }
    __shared__ float4 rs[256], rq[256];
    __shared__ float ts[128];
    rs[t] = s; rq[t] = q;
    __syncthreads();
    int fq = t & 31;   // feature quad index
    int rg = t >> 5;   // reduce group 0..7
    #pragma unroll
    for (int off = 4; off >= 1; off >>= 1) {
        if (rg < off) {
            float4 os = rs[t + off * 32], oq = rq[t + off * 32];
            s.x += os.x; s.y += os.y; s.z += os.z; s.w += os.w;
            q.x += oq.x; q.y += oq.y; q.z += oq.z; q.w += oq.w;
            rs[t] = s; rq[t] = q;
        }
        __syncthreads();
    }
    if (rg == 0) {
        float inv = 1.0f / (float)N;
        float sv[4] = { s.x, s.y, s.z, s.w };
        float qv[4] = { q.x, q.y, q.z, q.w };
        #pragma unroll
        for (int j = 0; j < 4; j++) {
            int f = 4 * fq + j;
            float m = sv[j] * inv;
            float var = qv[j] * inv - m * m;
            float sc = gamma[f] * rsqrtf(var + 1e-5f);
            aff_s[f] = sc;
            ts[f] = beta[f] - m * sc;
        }
    }
    __syncthreads();
    if (t < 128) {
        // c_f = sum_k ts[k] * Wnext[k][f]  (coalesced: consecutive t read consecutive f)
        float c = 0.f;
        for (int k = 0; k < 128; k++) c += ts[k] * Wnext[k * 128 + t];
        cvec[t] = c;
    }
}

// ---------------- pool: block per graph, 8-row-parallel float4 loads ----------------
__device__ __forceinline__ int lower_bound_i(const int* __restrict__ arr, int n, int val) {
    int lo = 0, hi = n;
    while (lo < hi) {
        int mid = (lo + hi) >> 1;
        if (arr[mid] < val) lo = mid + 1; else hi = mid;
    }
    return lo;
}

__global__ __launch_bounds__(256) void pool_kernel(const float* __restrict__ h,
                                                   const int* __restrict__ batch,
                                                   float* __restrict__ out, int N, int G) {
    int g = blockIdx.x;
    int lo = lower_bound_i(batch, N, g);
    int hi = lower_bound_i(batch, N, g + 1);
    int sl = threadIdx.x & 31;
    int rg = threadIdx.x >> 5;

    float4 acc = make_float4(0.f, 0.f, 0.f, 0.f);
    for (int n = lo + rg; n < hi; n += 8) {
        float4 v = ((const float4*)(h + (size_t)n * HDIM))[sl];
        acc.x += v.x; acc.y += v.y; acc.z += v.z; acc.w += v.w;
    }

    __shared__ float4 red[256];
    red[threadIdx.x] = acc;
    __syncthreads();
    if (rg < 4) {
        float4 o = red[threadIdx.x + 128];
        acc.x += o.x; acc.y += o.y; acc.z += o.z; acc.w += o.w;
        red[threadIdx.x] = acc;
    }
    __syncthreads();
    if (rg < 2) {
        float4 o = red[threadIdx.x + 64];
        acc.x += o.x; acc.y += o.y; acc.z += o.z; acc.w += o.w;
        red[threadIdx.x] = acc;
    }
    __syncthreads();
    if (rg == 0) {
        float4 o = red[threadIdx.x + 32];
        float inv = 1.0f / fmaxf((float)(hi - lo), 1.0f);
        float4 r;
        r.x = (acc.x + o.x) * inv;
        r.y = (acc.y + o.y) * inv;
        r.z = (acc.z + o.z) * inv;
        r.w = (acc.w + o.w) * inv;
        ((float4*)(out + (size_t)g * HDIM))[sl] = r;
    }
}

// ---------------- launch ----------------
extern "C" void kernel_launch(void* const* d_in, const int* in_sizes, int n_in,
                              void* d_out, int out_size, void* d_ws, size_t ws_size,
                              hipStream_t stream) {
    const float* x      = (const float*)d_in[0];
    const int*   ei     = (const int*)d_in[1];
    const int*   batch  = (const int*)d_in[2];
    const float* W_emb  = (const float*)d_in[3];
    const float* b_emb  = (const float*)d_in[4];
    const float* W_conv = (const float*)d_in[5];
    const float* b_conv = (const float*)d_in[6];
    const float* gamma  = (const float*)d_in[7];
    const float* beta   = (const float*)d_in[8];

    const int E = in_sizes[1] / 2;
    const int N = in_sizes[2];
    const int G = out_size / HDIM;
    const int DEPTH = 4;

    const int* srcp = ei;
    const int* dstp = ei + E;
    float* out = (float*)d_out;

    size_t NH = (size_t)N * HDIM;
    size_t npad = ((size_t)N + 63) & ~(size_t)63;
    size_t epad = ((size_t)E + 63) & ~(size_t)63;
    int nb = (N + 127) / 128;  // buckets (<= NBMAX)

    float* ws = (float*)d_ws;
    float* dinv    = ws;                            // npad
    int*   offs    = (int*)(dinv + npad);           // npad + 64
    int*   bases   = offs + npad + 64;              // NBMAX+1 (pad 1024)
    int*   cursor  = bases + 1024;                  // NBMAX
    int*   bcount  = cursor + NBMAX;                // NBMAX
    int*   csr     = bcount + NBMAX;                // epad
    unsigned* ebuf = (unsigned*)(csr + epad);       // epad
    float* Psum    = (float*)(ebuf + epad);         // NBS*128
    float* Qsum    = Psum + NBS * HDIM;             // NBS*128
    float* aff_s   = Qsum + NBS * HDIM;             // 128
    float* cvec    = aff_s + 128;                   // 128
    short* wt      = (short*)(cvec + 128);          // 5 * 2 * 16384 shorts
    float* hbuf    = (float*)(wt + 5 * 2 * 16384);  // NH floats (aliased as hi/lo shorts)
    __half* hws16  = (__half*)(hbuf + NH);          // NH halves
    short* hsplit  = (short*)hbuf;                  // [NH hi shorts][NH lo shorts] == NH floats

    // ---- weight split (5 matrices, one launch) ----
    wsplit_all<<<(5 * 16384 + 255) / 256, 256, 0, stream>>>(W_emb, W_conv, wt);

    // ---- CSR build (two-level binning) ----
    hipMemsetAsync(bcount, 0, NBMAX * sizeof(int), stream);
    bucket_hist<<<256, 256, 0, stream>>>(dstp, bcount, E);
    bucket_scan<<<1, 256, 0, stream>>>(bcount, bases, cursor, E);
    bucket_scatter<<<(E + CHUNK - 1) / CHUNK, 256, 0, stream>>>(srcp, dstp, cursor, ebuf, E);
    bucket_finalize<<<nb, 256, 0, stream>>>(ebuf, bases, csr, offs, dinv, N, E);

    int gemm_blocks = (N + 127) / 128;
    int gather_blocks = (N + 3) / 4;

    // ---- embedding: hsplit = split(x @ W_emb + b_emb) ----
    gemm_mfma<false, true><<<gemm_blocks, 256, 0, stream>>>(x, wt, wt + 16384, b_emb,
                                                            nullptr, hsplit, NH, N);

    for (int l = 0; l < DEPTH; l++) {
        short* whi = wt + (size_t)(l + 1) * 32768;
        // hws16 = fp16( dinv .* (h @ W'[l] + c) )   (c only for l>0; W' pre-scaled for l>0)
        gemm_mfma<true, false><<<gemm_blocks, 256, 0, stream>>>(hsplit, whi, whi + 16384,
                                                                (l > 0) ? cvec : nullptr,
                                                                dinv, hws16, NH, N);
        if (l < DEPTH - 1) {
            gather_kernel<true><<<gather_blocks, 256, 0, stream>>>(hws16, csr, offs, dinv,
                                                                   b_conv + (size_t)l * HDIM,
                                                                   hsplit, NH, N);
            bn_stats2<<<NBS, 256, 0, stream>>>(hsplit, Psum, Qsum, NH, N);
            const float* Wnext = W_conv + (size_t)(l + 1) * 16384;
            bn_finalize_w<<<1, 256, 0, stream>>>(Psum, Qsum, gamma + (size_t)l * HDIM,
                                                 beta + (size_t)l * HDIM, Wnext,
                                                 aff_s, cvec, N, NBS);
            wsplit_scaled<<<64, 256, 0, stream>>>(Wnext, aff_s, wt + (size_t)(l + 2) * 32768);
        } else {
            gather_kernel<false><<<gather_blocks, 256, 0, stream>>>(hws16, csr, offs, dinv,
                                                                    b_conv + (size_t)l * HDIM,
                                                                    hbuf, NH, N);
        }
    }

    pool_kernel<<<G, 256, 0, stream>>>(hbuf, batch, out, N, G);
}

// Round 18
// 387.144 us; speedup vs baseline: 1.0668x; 1.0668x over previous
//
#include <hip/hip_runtime.h>
#include <hip/hip_fp16.h>
#include <math.h>

#define HDIM 128
#define BKT_SHIFT 7          // 128 nodes per bucket
#define NBMAX 512            // max buckets (N <= 65536)
#define CHUNK 4096           // edges per bucket_scatter block
#define NBS 512              // bn_stats blocks (= partial rows)

typedef __attribute__((ext_vector_type(8))) short bf16x8;
typedef __attribute__((ext_vector_type(4))) float f32x4;

union U4 { unsigned int u[4]; bf16x8 v; };

__device__ __forceinline__ unsigned int cvt_pk_bf16(float a, float b) {
    unsigned int r;
    asm("v_cvt_pk_bf16_f32 %0, %1, %2" : "=v"(r) : "v"(a), "v"(b));
    return r;
}

// split 8 fp32 -> hi bf16x8 + lo bf16x8 (x ~= hi + lo, error ~2^-17 |x|)
__device__ __forceinline__ void split8(const float* v, bf16x8& ah, bf16x8& al) {
    U4 H, L;
    #pragma unroll
    for (int p = 0; p < 4; p++) {
        unsigned int h = cvt_pk_bf16(v[2 * p], v[2 * p + 1]);
        H.u[p] = h;
        float h0 = __uint_as_float(h << 16);
        float h1 = __uint_as_float(h & 0xFFFF0000u);
        L.u[p] = cvt_pk_bf16(v[2 * p] - h0, v[2 * p + 1] - h1);
    }
    ah = H.v; al = L.v;
}

// ================= CSR build via two-level binning =================
__global__ __launch_bounds__(256) void bucket_hist(const int* __restrict__ dst,
                                                   int* __restrict__ bcount, int E) {
    __shared__ int h[NBMAX];
    int t = threadIdx.x;
    for (int b = t; b < NBMAX; b += 256) h[b] = 0;
    __syncthreads();
    int i = blockIdx.x * blockDim.x + t;
    int stride = gridDim.x * blockDim.x;
    for (; i < E; i += stride) atomicAdd(&h[dst[i] >> BKT_SHIFT], 1);
    __syncthreads();
    for (int b = t; b < NBMAX; b += 256) {
        int c = h[b];
        if (c) atomicAdd(&bcount[b], c);
    }
}

__global__ __launch_bounds__(256) void bucket_scan(const int* __restrict__ bcount,
                                                   int* __restrict__ bases,
                                                   int* __restrict__ cursor, int E) {
    int t = threadIdx.x;
    int v0 = bcount[2 * t], v1 = bcount[2 * t + 1];
    int s = v0 + v1;
    __shared__ int ss[256];
    ss[t] = s; __syncthreads();
    #pragma unroll
    for (int off = 1; off < 256; off <<= 1) {
        int u = (t >= off) ? ss[t - off] : 0;
        __syncthreads();
        ss[t] += u;
        __syncthreads();
    }
    int ex = ss[t] - s;
    bases[2 * t] = ex;          cursor[2 * t] = ex;
    bases[2 * t + 1] = ex + v0; cursor[2 * t + 1] = ex + v0;
    if (t == 255) bases[NBMAX] = E;
}

// pack: bits 24..30 = dst&127, bits 0..23 = src  (requires N < 2^24)
__global__ __launch_bounds__(256) void bucket_scatter(const int* __restrict__ src,
                                                      const int* __restrict__ dst,
                                                      int* __restrict__ cursor,
                                                      unsigned* __restrict__ ebuf, int E) {
    __shared__ unsigned sbuf[CHUNK];
    __shared__ int hist[NBMAX], hbase[NBMAX], gbase[NBMAX], cnt2[NBMAX];
    __shared__ int ss[256];
    int t = threadIdx.x;
    int start = blockIdx.x * CHUNK;
    int n = min(CHUNK, E - start);

    for (int b = t; b < NBMAX; b += 256) { hist[b] = 0; cnt2[b] = 0; }
    __syncthreads();
    for (int i = t; i < n; i += 256) atomicAdd(&hist[dst[start + i] >> BKT_SHIFT], 1);
    __syncthreads();

    int v0 = hist[2 * t], v1 = hist[2 * t + 1];
    int s = v0 + v1;
    ss[t] = s; __syncthreads();
    #pragma unroll
    for (int off = 1; off < 256; off <<= 1) {
        int u = (t >= off) ? ss[t - off] : 0;
        __syncthreads();
        ss[t] += u;
        __syncthreads();
    }
    int ex = ss[t] - s;
    hbase[2 * t] = ex;
    hbase[2 * t + 1] = ex + v0;
    if (v0 > 0) gbase[2 * t] = atomicAdd(&cursor[2 * t], v0);
    if (v1 > 0) gbase[2 * t + 1] = atomicAdd(&cursor[2 * t + 1], v1);
    __syncthreads();

    for (int i = t; i < n; i += 256) {
        int d = dst[start + i];
        int bkt = d >> BKT_SHIFT;
        unsigned p = ((unsigned)(d & 127) << 24) | (unsigned)src[start + i];
        int pos = atomicAdd(&cnt2[bkt], 1);
        sbuf[hbase[bkt] + pos] = p;
    }
    __syncthreads();

    for (int b = t; b < NBMAX; b += 256) {
        int c = hist[b], hb = hbase[b], gb = gbase[b];
        for (int j = 0; j < c; j++) ebuf[gb + j] = sbuf[hb + j];
    }
}

__global__ __launch_bounds__(256) void bucket_finalize(const unsigned* __restrict__ ebuf,
                                                       const int* __restrict__ bases,
                                                       int* __restrict__ csr,
                                                       int* __restrict__ offs,
                                                       float* __restrict__ dinv,
                                                       int N, int E) {
    int b = blockIdx.x;
    int beg = bases[b], end = bases[b + 1];
    __shared__ int hist[128], pre[128], cnt2[128];
    int t = threadIdx.x;
    if (t < 128) { hist[t] = 0; cnt2[t] = 0; }
    __syncthreads();
    for (int i = beg + t; i < end; i += 256)
        atomicAdd(&hist[(ebuf[i] >> 24) & 127], 1);
    __syncthreads();
    if (t < 128) pre[t] = hist[t];
    __syncthreads();
    #pragma unroll
    for (int off = 1; off < 128; off <<= 1) {
        int v = (t < 128 && t >= off) ? pre[t - off] : 0;
        __syncthreads();
        if (t < 128) pre[t] += v;
        __syncthreads();
    }
    if (t < 128) {
        int node = b * 128 + t;
        if (node < N) {
            int ex = pre[t] - hist[t];
            offs[node] = beg + ex;
            dinv[node] = rsqrtf((float)hist[t] + 1.0f);
        }
    }
    if (b == 0 && t == 0) offs[N] = E;
    __syncthreads();
    for (int i = beg + t; i < end; i += 256) {
        unsigned p = ebuf[i];
        int dl = (p >> 24) & 127;
        int pos = atomicAdd(&cnt2[dl], 1);
        csr[beg + (pre[dl] - hist[dl]) + pos] = (int)(p & 0xFFFFFFu);
    }
}

// ---------------- weight split (all 5 matrices in one launch) ----------------
// W[k][n] fp32 -> Wh/Wl[n][k] bf16 (RNE); matrix m: 0=emb, 1..4=conv[l]
__global__ void wsplit_all(const float* __restrict__ W_emb, const float* __restrict__ W_conv,
                           short* __restrict__ wt) {
    int gid = blockIdx.x * 256 + threadIdx.x;
    if (gid >= 5 * 16384) return;
    int m = gid >> 14;
    int i = gid & 16383;               // i = n*128 + k
    int n = i >> 7, k = i & 127;
    const float* src = (m == 0) ? W_emb : (W_conv + (size_t)(m - 1) * 16384);
    float v = src[k * 128 + n];
    unsigned int u = __float_as_uint(v);
    unsigned int hi = (u + 0x7FFFu + ((u >> 16) & 1)) & 0xFFFF0000u;
    float hf = __uint_as_float(hi);
    float lo = v - hf;
    unsigned int ul = __float_as_uint(lo);
    unsigned int lo16 = (ul + 0x7FFFu + ((ul >> 16) & 1)) >> 16;
    short* Whi = wt + (size_t)m * 32768;
    Whi[i] = (short)(hi >> 16);
    Whi[16384 + i] = (short)lo16;
}

// ---------------- MFMA GEMM: C[N x 128] = affine(A)[N x 128] @ W[128 x 128] ----------------
// Split-bf16 3-product: D += Ah*Bh + Ah*Bl + Al*Bh  (~fp32 precision).
// OUT_F16: write fp16 (pre-aggregation intermediate); else fp32.
template <bool OUT_F16>
__global__ __launch_bounds__(256) void gemm_mfma(const float* __restrict__ A,
                                                 const short* __restrict__ Wh,
                                                 const short* __restrict__ Wl,
                                                 const float* __restrict__ aff_s,
                                                 const float* __restrict__ aff_t,
                                                 const float* __restrict__ bias,
                                                 const float* __restrict__ rowscale,
                                                 void* __restrict__ outp, int N) {
    int w = threadIdx.x >> 6;
    int lane = threadIdx.x & 63;
    int l15 = lane & 15, lg = lane >> 4;
    int r0 = blockIdx.x * 128 + (w >> 1) * 64;
    int c0 = (w & 1) * 64;

    f32x4 acc[4][4];
    #pragma unroll
    for (int tc = 0; tc < 4; tc++) {
        float bz = bias ? bias[c0 + tc * 16 + l15] : 0.0f;
        #pragma unroll
        for (int tr = 0; tr < 4; tr++) {
            acc[tr][tc][0] = bz; acc[tr][tc][1] = bz;
            acc[tr][tc][2] = bz; acc[tr][tc][3] = bz;
        }
    }

    #pragma unroll
    for (int kt = 0; kt < 4; kt++) {
        int kk = kt * 32 + lg * 8;   // this lane's k base

        bf16x8 bh[4], bl[4];
        #pragma unroll
        for (int tc = 0; tc < 4; tc++) {
            int n = c0 + tc * 16 + l15;
            bh[tc] = *(const bf16x8*)(Wh + n * 128 + kk);
            bl[tc] = *(const bf16x8*)(Wl + n * 128 + kk);
        }

        float sv[8], tv[8];
        if (aff_s) {
            *(float4*)&sv[0] = *(const float4*)(aff_s + kk);
            *(float4*)&sv[4] = *(const float4*)(aff_s + kk + 4);
            *(float4*)&tv[0] = *(const float4*)(aff_t + kk);
            *(float4*)&tv[4] = *(const float4*)(aff_t + kk + 4);
        }

        bf16x8 ah[4], al[4];
        #pragma unroll
        for (int tr = 0; tr < 4; tr++) {
            int row = min(r0 + tr * 16 + l15, N - 1);
            const float* ap = A + (size_t)row * 128 + kk;
            float v[8];
            *(float4*)&v[0] = *(const float4*)ap;
            *(float4*)&v[4] = *(const float4*)(ap + 4);
            if (aff_s) {
                #pragma unroll
                for (int j = 0; j < 8; j++) v[j] = fmaf(v[j], sv[j], tv[j]);
            }
            split8(v, ah[tr], al[tr]);
        }

        #pragma unroll
        for (int tr = 0; tr < 4; tr++) {
            #pragma unroll
            for (int tc = 0; tc < 4; tc++) {
                acc[tr][tc] = __builtin_amdgcn_mfma_f32_16x16x32_bf16(ah[tr], bh[tc], acc[tr][tc], 0, 0, 0);
                acc[tr][tc] = __builtin_amdgcn_mfma_f32_16x16x32_bf16(ah[tr], bl[tc], acc[tr][tc], 0, 0, 0);
                acc[tr][tc] = __builtin_amdgcn_mfma_f32_16x16x32_bf16(al[tr], bh[tc], acc[tr][tc], 0, 0, 0);
            }
        }
    }

    // C/D layout: row = (lane>>4)*4 + reg, col = lane&15 (per 16x16 tile)
    #pragma unroll
    for (int tr = 0; tr < 4; tr++) {
        #pragma unroll
        for (int r = 0; r < 4; r++) {
            int row = r0 + tr * 16 + lg * 4 + r;
            if (row < N) {
                float sc = rowscale ? rowscale[row] : 1.0f;
                #pragma unroll
                for (int tc = 0; tc < 4; tc++) {
                    int col = c0 + tc * 16 + l15;
                    float val = acc[tr][tc][r] * sc;
                    if (OUT_F16) {
                        ((__half*)outp)[(size_t)row * 128 + col] = __float2half(val);
                    } else {
                        ((float*)outp)[(size_t)row * 128 + col] = val;
                    }
                }
            }
        }
    }
}

// ---------------- gather (fp16 in, fp32 out), 4 edges/wave via 16B lane loads ----------------
// wave = one node. Quarter q (lanes q*16..q*16+15) takes edges lo+q, lo+q+4, ...
// lane sq (0..15) covers features 8sq..8sq+7 via one uint4 (16B) load per row.
__global__ __launch_bounds__(256) void gather_kernel(const __half* __restrict__ hws,
                                                     const int* __restrict__ csr_src,
                                                     const int* __restrict__ offs,
                                                     const float* __restrict__ dinv,
                                                     const float* __restrict__ bias,
                                                     float* __restrict__ out,
                                                     int N, int relu) {
    int lane = threadIdx.x & 63;
    int q = lane >> 4;        // quarter 0..3
    int sq = lane & 15;       // sub-lane: features 8sq..8sq+7
    int node = blockIdx.x * 4 + (threadIdx.x >> 6);
    if (node >= N) return;
    int lo = offs[node], hi = offs[node + 1];

    const uint4* base = (const uint4*)hws;  // row s = base + s*16; lane offset sq
    float4 a0 = make_float4(0.f, 0.f, 0.f, 0.f), a1 = a0;

    #define ACCUM_U4(u)  do {                                                    \
        float2 p0 = __half22float2(*(__half2*)&(u).x);                           \
        float2 p1 = __half22float2(*(__half2*)&(u).y);                           \
        float2 p2 = __half22float2(*(__half2*)&(u).z);                           \
        float2 p3 = __half22float2(*(__half2*)&(u).w);                           \
        a0.x += p0.x; a0.y += p0.y; a0.z += p1.x; a0.w += p1.y;                  \
        a1.x += p2.x; a1.y += p2.y; a1.z += p3.x; a1.w += p3.y;                  \
    } while (0)

    int j = lo + q;
    for (; j + 12 < hi; j += 16) {
        int s0 = csr_src[j], s1 = csr_src[j + 4], s2 = csr_src[j + 8], s3 = csr_src[j + 12];
        uint4 u0 = base[(size_t)s0 * 16 + sq];
        uint4 u1 = base[(size_t)s1 * 16 + sq];
        uint4 u2 = base[(size_t)s2 * 16 + sq];
        uint4 u3 = base[(size_t)s3 * 16 + sq];
        ACCUM_U4(u0); ACCUM_U4(u1); ACCUM_U4(u2); ACCUM_U4(u3);
    }
    for (; j < hi; j += 4) {
        int s = csr_src[j];
        uint4 u = base[(size_t)s * 16 + sq];
        ACCUM_U4(u);
    }
    // self-loop: quarter 0 only (butterfly below sums all quarters once)
    if (q == 0) {
        uint4 u = base[(size_t)node * 16 + sq];
        ACCUM_U4(u);
    }
    #undef ACCUM_U4

    // combine quarters: lane^16, lane^32
    a0.x += __shfl_xor(a0.x, 16); a0.y += __shfl_xor(a0.y, 16);
    a0.z += __shfl_xor(a0.z, 16); a0.w += __shfl_xor(a0.w, 16);
    a1.x += __shfl_xor(a1.x, 16); a1.y += __shfl_xor(a1.y, 16);
    a1.z += __shfl_xor(a1.z, 16); a1.w += __shfl_xor(a1.w, 16);
    a0.x += __shfl_xor(a0.x, 32); a0.y += __shfl_xor(a0.y, 32);
    a0.z += __shfl_xor(a0.z, 32); a0.w += __shfl_xor(a0.w, 32);
    a1.x += __shfl_xor(a1.x, 32); a1.y += __shfl_xor(a1.y, 32);
    a1.z += __shfl_xor(a1.z, 32); a1.w += __shfl_xor(a1.w, 32);

    if (q == 0) {
        float di = dinv[node];
        float4 b0 = ((const float4*)bias)[2 * sq];
        float4 b1 = ((const float4*)bias)[2 * sq + 1];
        float4 o0, o1;
        o0.x = di * a0.x + b0.x; o0.y = di * a0.y + b0.y;
        o0.z = di * a0.z + b0.z; o0.w = di * a0.w + b0.w;
        o1.x = di * a1.x + b1.x; o1.y = di * a1.y + b1.y;
        o1.z = di * a1.z + b1.z; o1.w = di * a1.w + b1.w;
        if (relu) {
            o0.x = fmaxf(o0.x, 0.f); o0.y = fmaxf(o0.y, 0.f);
            o0.z = fmaxf(o0.z, 0.f); o0.w = fmaxf(o0.w, 0.f);
            o1.x = fmaxf(o1.x, 0.f); o1.y = fmaxf(o1.y, 0.f);
            o1.z = fmaxf(o1.z, 0.f); o1.w = fmaxf(o1.w, 0.f);
        }
        ((float4*)(out + (size_t)node * HDIM))[2 * sq] = o0;
        ((float4*)(out + (size_t)node * HDIM))[2 * sq + 1] = o1;
    }
}

// ---------------- BN stats: per-block partials, 4-way MLP, no atomics ----------------
__global__ __launch_bounds__(256) void bn_stats_p(const float* __restrict__ h,
                                                  float* __restrict__ Psum,
                                                  float* __restrict__ Qsum, int N) {
    int sl = threadIdx.x & 31;   // feature quad 4sl..4sl+3
    int rg = threadIdx.x >> 5;   // row group 0..7
    float4 s = make_float4(0.f, 0.f, 0.f, 0.f), q = s;
    const int S = NBS * 8;       // 4096
    for (int n = blockIdx.x * 8 + rg; n < N; n += 4 * S) {
        int n1 = n + S, n2 = n + 2 * S, n3 = n + 3 * S;
        float4 v0 = ((const float4*)(h + (size_t)n * HDIM))[sl];
        float4 v1 = (n1 < N) ? ((const float4*)(h + (size_t)n1 * HDIM))[sl] : make_float4(0.f, 0.f, 0.f, 0.f);
        float4 v2 = (n2 < N) ? ((const float4*)(h + (size_t)n2 * HDIM))[sl] : make_float4(0.f, 0.f, 0.f, 0.f);
        float4 v3 = (n3 < N) ? ((const float4*)(h + (size_t)n3 * HDIM))[sl] : make_float4(0.f, 0.f, 0.f, 0.f);
        s.x += v0.x + v1.x + v2.x + v3.x;
        s.y += v0.y + v1.y + v2.y + v3.y;
        s.z += v0.z + v1.z + v2.z + v3.z;
        s.w += v0.w + v1.w + v2.w + v3.w;
        q.x += v0.x * v0.x + v1.x * v1.x + v2.x * v2.x + v3.x * v3.x;
        q.y += v0.y * v0.y + v1.y * v1.y + v2.y * v2.y + v3.y * v3.y;
        q.z += v0.z * v0.z + v1.z * v1.z + v2.z * v2.z + v3.z * v3.z;
        q.w += v0.w * v0.w + v1.w * v1.w + v2.w * v2.w + v3.w * v3.w;
    }
    __shared__ float4 rs[256], rq[256];
    rs[threadIdx.x] = s; rq[threadIdx.x] = q;
    __syncthreads();
    #pragma unroll
    for (int off = 4; off >= 1; off >>= 1) {
        if (rg < off) {
            float4 os = rs[threadIdx.x + off * 32], oq = rq[threadIdx.x + off * 32];
            s.x += os.x; s.y += os.y; s.z += os.z; s.w += os.w;
            q.x += oq.x; q.y += oq.y; q.z += oq.z; q.w += oq.w;
            rs[threadIdx.x] = s; rq[threadIdx.x] = q;
        }
        __syncthreads();
    }
    if (rg == 0) {
        size_t base = (size_t)blockIdx.x * HDIM;
        ((float4*)(Psum + base))[sl] = s;
        ((float4*)(Qsum + base))[sl] = q;
    }
}

// ---------------- bn finalize: COALESCED parallel reduce -> aff_s, aff_t ----------------
__global__ __launch_bounds__(256) void bn_finalize_p(const float* __restrict__ Psum,
                                                     const float* __restrict__ Qsum,
                                                     const float* __restrict__ gamma,
                                                     const float* __restrict__ beta,
                                                     float* __restrict__ aff_s,
                                                     float* __restrict__ aff_t,
                                                     int N, int nblk) {
    int t = threadIdx.x;
    int total4 = nblk * 32;  // float4 elements per array
    float4 s = make_float4(0.f, 0.f, 0.f, 0.f), q = s;
    for (int i = t; i < total4; i += 256) {
        float4 p = ((const float4*)Psum)[i];
        float4 r = ((const float4*)Qsum)[i];
        s.x += p.x; s.y += p.y; s.z += p.z; s.w += p.w;
        q.x += r.x; q.y += r.y; q.z += r.z; q.w += r.w;
    }
    __shared__ float4 rs[256], rq[256];
    rs[t] = s; rq[t] = q;
    __syncthreads();
    int fq = t & 31;   // feature quad index
    int rg = t >> 5;   // reduce group 0..7
    #pragma unroll
    for (int off = 4; off >= 1; off >>= 1) {
        if (rg < off) {
            float4 os = rs[t + off * 32], oq = rq[t + off * 32];
            s.x += os.x; s.y += os.y; s.z += os.z; s.w += os.w;
            q.x += oq.x; q.y += oq.y; q.z += oq.z; q.w += oq.w;
            rs[t] = s; rq[t] = q;
        }
        __syncthreads();
    }
    if (rg == 0) {
        float inv = 1.0f / (float)N;
        float sv[4] = { s.x, s.y, s.z, s.w };
        float qv[4] = { q.x, q.y, q.z, q.w };
        #pragma unroll
        for (int j = 0; j < 4; j++) {
            int f = 4 * fq + j;
            float m = sv[j] * inv;
            float var = qv[j] * inv - m * m;
            float sc = gamma[f] * rsqrtf(var + 1e-5f);
            aff_s[f] = sc;
            aff_t[f] = beta[f] - m * sc;
        }
    }
}

// ---------------- pool: block per graph, 8-row-parallel float4 loads ----------------
__device__ __forceinline__ int lower_bound_i(const int* __restrict__ arr, int n, int val) {
    int lo = 0, hi = n;
    while (lo < hi) {
        int mid = (lo + hi) >> 1;
        if (arr[mid] < val) lo = mid + 1; else hi = mid;
    }
    return lo;
}

__global__ __launch_bounds__(256) void pool_kernel(const float* __restrict__ h,
                                                   const int* __restrict__ batch,
                                                   float* __restrict__ out, int N, int G) {
    int g = blockIdx.x;
    int lo = lower_bound_i(batch, N, g);
    int hi = lower_bound_i(batch, N, g + 1);
    int sl = threadIdx.x & 31;
    int rg = threadIdx.x >> 5;

    float4 acc = make_float4(0.f, 0.f, 0.f, 0.f);
    for (int n = lo + rg; n < hi; n += 8) {
        float4 v = ((const float4*)(h + (size_t)n * HDIM))[sl];
        acc.x += v.x; acc.y += v.y; acc.z += v.z; acc.w += v.w;
    }

    __shared__ float4 red[256];
    red[threadIdx.x] = acc;
    __syncthreads();
    if (rg < 4) {
        float4 o = red[threadIdx.x + 128];
        acc.x += o.x; acc.y += o.y; acc.z += o.z; acc.w += o.w;
        red[threadIdx.x] = acc;
    }
    __syncthreads();
    if (rg < 2) {
        float4 o = red[threadIdx.x + 64];
        acc.x += o.x; acc.y += o.y; acc.z += o.z; acc.w += o.w;
        red[threadIdx.x] = acc;
    }
    __syncthreads();
    if (rg == 0) {
        float4 o = red[threadIdx.x + 32];
        float inv = 1.0f / fmaxf((float)(hi - lo), 1.0f);
        float4 r;
        r.x = (acc.x + o.x) * inv;
        r.y = (acc.y + o.y) * inv;
        r.z = (acc.z + o.z) * inv;
        r.w = (acc.w + o.w) * inv;
        ((float4*)(out + (size_t)g * HDIM))[sl] = r;
    }
}

// ---------------- launch ----------------
extern "C" void kernel_launch(void* const* d_in, const int* in_sizes, int n_in,
                              void* d_out, int out_size, void* d_ws, size_t ws_size,
                              hipStream_t stream) {
    const float* x      = (const float*)d_in[0];
    const int*   ei     = (const int*)d_in[1];
    const int*   batch  = (const int*)d_in[2];
    const float* W_emb  = (const float*)d_in[3];
    const float* b_emb  = (const float*)d_in[4];
    const float* W_conv = (const float*)d_in[5];
    const float* b_conv = (const float*)d_in[6];
    const float* gamma  = (const float*)d_in[7];
    const float* beta   = (const float*)d_in[8];

    const int E = in_sizes[1] / 2;
    const int N = in_sizes[2];
    const int G = out_size / HDIM;
    const int DEPTH = 4;

    const int* srcp = ei;
    const int* dstp = ei + E;
    float* out = (float*)d_out;

    size_t NH = (size_t)N * HDIM;
    size_t npad = ((size_t)N + 63) & ~(size_t)63;
    size_t epad = ((size_t)E + 63) & ~(size_t)63;
    int nb = (N + 127) / 128;  // buckets (<= NBMAX)

    float* ws = (float*)d_ws;
    float* dinv    = ws;                            // npad
    int*   offs    = (int*)(dinv + npad);           // npad + 64
    int*   bases   = offs + npad + 64;              // NBMAX+1 (pad 1024)
    int*   cursor  = bases + 1024;                  // NBMAX
    int*   bcount  = cursor + NBMAX;                // NBMAX
    int*   csr     = bcount + NBMAX;                // epad
    unsigned* ebuf = (unsigned*)(csr + epad);       // epad
    float* Psum    = (float*)(ebuf + epad);         // NBS*128
    float* Qsum    = Psum + NBS * HDIM;             // NBS*128
    float* aff_s   = Qsum + NBS * HDIM;             // 128
    float* aff_t   = aff_s + 128;                   // 128
    short* wt      = (short*)(aff_t + 128);         // 5 * 2 * 16384 shorts
    float* hbuf    = (float*)(wt + 5 * 2 * 16384);  // NH floats
    __half* hws16  = (__half*)(hbuf + NH);          // NH halves

    // ---- weight split (5 matrices, one launch) ----
    wsplit_all<<<(5 * 16384 + 255) / 256, 256, 0, stream>>>(W_emb, W_conv, wt);

    // ---- CSR build (two-level binning) ----
    hipMemsetAsync(bcount, 0, NBMAX * sizeof(int), stream);
    bucket_hist<<<256, 256, 0, stream>>>(dstp, bcount, E);
    bucket_scan<<<1, 256, 0, stream>>>(bcount, bases, cursor, E);
    bucket_scatter<<<(E + CHUNK - 1) / CHUNK, 256, 0, stream>>>(srcp, dstp, cursor, ebuf, E);
    bucket_finalize<<<nb, 256, 0, stream>>>(ebuf, bases, csr, offs, dinv, N, E);

    int gemm_blocks = (N + 127) / 128;
    int gather_blocks = (N + 3) / 4;

    // ---- embedding: hbuf = x @ W_emb + b_emb (fp32 out) ----
    gemm_mfma<false><<<gemm_blocks, 256, 0, stream>>>(x, wt, wt + 16384, nullptr, nullptr,
                                                      b_emb, nullptr, hbuf, N);

    for (int l = 0; l < DEPTH; l++) {
        short* whi = wt + (size_t)(l + 1) * 32768;
        // hws16 = fp16( dinv .* (BN_affine(hbuf) @ W_conv[l]) )   (affine only for l>0)
        gemm_mfma<true><<<gemm_blocks, 256, 0, stream>>>(hbuf, whi, whi + 16384,
                                                         (l > 0) ? aff_s : nullptr,
                                                         (l > 0) ? aff_t : nullptr,
                                                         nullptr, dinv, hws16, N);
        gather_kernel<<<gather_blocks, 256, 0, stream>>>(hws16, csr, offs, dinv,
                                                         b_conv + (size_t)l * HDIM, hbuf,
                                                         N, (l < DEPTH - 1) ? 1 : 0);
        if (l < DEPTH - 1) {
            bn_stats_p<<<NBS, 256, 0, stream>>>(hbuf, Psum, Qsum, N);
            bn_finalize_p<<<1, 256, 0, stream>>>(Psum, Qsum, gamma + (size_t)l * HDIM,
                                                 beta + (size_t)l * HDIM, aff_s, aff_t,
                                                 N, NBS);
        }
    }

    pool_kernel<<<G, 256, 0, stream>>>(hbuf, batch, out, N, G);
}